// Round 3
// baseline (7501.232 us; speedup 1.0000x reference)
//
#include <hip/hip_runtime.h>
#include <hip/hip_bf16.h>

typedef __hip_bfloat16 bf16;

#define HWp 4800   // H*W
#define Wd 80
#define Hd 60
#define Fh 64      // hidden channels
#define Bn 4
#define Tn 12

__device__ __forceinline__ float b2f(bf16 v){ return __bfloat162float(v); }
__device__ __forceinline__ bf16 f2b(float v){ return __float2bfloat16(v); }

// weights [256][CIN][9] f32 -> [fo][g][CIN][9] f32 (gate-major -> fo-major)
__global__ void perm_w_kernel(const float* __restrict__ src, float* __restrict__ dst, int cin){
    int idx = blockIdx.x*256 + threadIdx.x;
    int n = 256*cin*9;
    if (idx >= n) return;
    int co = idx/(cin*9); int r = idx - co*(cin*9);
    int g = co >> 6, fo = co & 63;
    dst[(fo*4+g)*cin*9 + r] = src[idx];
}

__global__ void perm_bias_kernel(const float* __restrict__ src, float* __restrict__ dst){
    int idx = threadIdx.x; // 256
    int g = idx >> 6, fo = idx & 63;
    dst[fo*4+g] = src[idx];
}

__global__ void copy_f32_kernel(const float* __restrict__ src, float* __restrict__ dst, int n){
    int idx = blockIdx.x*256+threadIdx.x;
    if (idx < n) dst[idx] = src[idx];
}

__global__ void f32_to_b16_kernel(const float* __restrict__ src, bf16* __restrict__ dst, int n){
    int idx = blockIdx.x*256+threadIdx.x;
    if (idx < n) dst[idx] = f2b(src[idx]);
}

// copy f32 h slice [B][F][HW] from b-strided src to contiguous dst
__global__ void copy_h_f32_kernel(const float* __restrict__ src, size_t bstride, float* __restrict__ dst){
    int idx = blockIdx.x*256+threadIdx.x;
    int n = Bn*Fh*HWp;
    if (idx >= n) return;
    int b = idx/(Fh*HWp); int r = idx - b*(Fh*HWp);
    dst[idx] = src[(size_t)b*bstride + r];
}

// input conv for all (b,t): z = conv_sym(x, W) + bias, 4 gates per thread
template<int CIN, bool IN_BF>
__global__ void zx_kernel(const void* __restrict__ xin_,  // [B*T][CIN][HW]
                          const float* __restrict__ Wf,   // [64][4][CIN][9]
                          const float* __restrict__ bias, // [64][4]
                          bf16* __restrict__ zx)          // [B*T][256][HW]
{
    int p = blockIdx.x*blockDim.x + threadIdx.x;
    if (p >= HWp) return;
    int fo = blockIdx.y, bt = blockIdx.z;
    int y = p / Wd, x = p - y*Wd;
    const float* wf = Wf + fo*4*CIN*9;
    float acc[4] = {bias[fo*4+0], bias[fo*4+1], bias[fo*4+2], bias[fo*4+3]};
    // symmetric pad of 1 == clamp indexing
    int ym = (y > 0 ? y-1 : 0)*Wd, y0 = y*Wd, yp = (y < Hd-1 ? y+1 : Hd-1)*Wd;
    int xm = (x > 0 ? x-1 : 0),    xp = (x < Wd-1 ? x+1 : Wd-1);
    for (int ci = 0; ci < CIN; ++ci){
        float v[9];
        if (IN_BF){
            const bf16* ic = (const bf16*)xin_ + ((size_t)bt*CIN + ci)*HWp;
            v[0]=b2f(ic[ym+xm]); v[1]=b2f(ic[ym+x]); v[2]=b2f(ic[ym+xp]);
            v[3]=b2f(ic[y0+xm]); v[4]=b2f(ic[y0+x]); v[5]=b2f(ic[y0+xp]);
            v[6]=b2f(ic[yp+xm]); v[7]=b2f(ic[yp+x]); v[8]=b2f(ic[yp+xp]);
        } else {
            const float* ic = (const float*)xin_ + ((size_t)bt*CIN + ci)*HWp;
            v[0]=ic[ym+xm]; v[1]=ic[ym+x]; v[2]=ic[ym+xp];
            v[3]=ic[y0+xm]; v[4]=ic[y0+x]; v[5]=ic[y0+xp];
            v[6]=ic[yp+xm]; v[7]=ic[yp+x]; v[8]=ic[yp+xp];
        }
        #pragma unroll
        for (int g = 0; g < 4; ++g){
            const float* w = wf + (g*CIN+ci)*9;
            acc[g] += v[0]*w[0]+v[1]*w[1]+v[2]*w[2]
                    + v[3]*w[3]+v[4]*w[4]+v[5]*w[5]
                    + v[6]*w[6]+v[7]*w[7]+v[8]*w[8];
        }
    }
    size_t zbase = (size_t)bt*256*HWp + p;
    #pragma unroll
    for (int g = 0; g < 4; ++g)
        zx[zbase + (size_t)(g*64+fo)*HWp] = f2b(acc[g]);
}

// one LSTM timestep: recurrent conv (zero-pad SAME) + gates + state update.
// Writes h as bf16 (recurrence) and optionally f32 (final output buffer).
template<bool WRITE_F32>
__global__ void rec_kernel(const bf16* __restrict__ hprev, size_t h_bstride,
                           const float* __restrict__ Uf,   // [64][4][64][9]
                           const bf16* __restrict__ zx_t, size_t zx_bstride,
                           float* __restrict__ c,          // [B][64][HW]
                           bf16* __restrict__ hout, size_t ho_bstride,
                           float* __restrict__ fout, size_t f_bstride)
{
    int p = blockIdx.x*blockDim.x + threadIdx.x;
    if (p >= HWp) return;
    int fo = blockIdx.y, b = blockIdx.z;
    int y = p / Wd, x = p - y*Wd;
    const bf16* h = hprev + (size_t)b*h_bstride;
    const float* uf = Uf + fo*4*Fh*9;
    float acc[4] = {0.f,0.f,0.f,0.f};
    bool ymok = (y > 0), ypok = (y < Hd-1), xmok = (x > 0), xpok = (x < Wd-1);
    for (int ci = 0; ci < Fh; ++ci){
        const bf16* hc = h + ci*HWp;
        float v[9];
        v[0] = (ymok&&xmok)? b2f(hc[p-Wd-1]) : 0.f;
        v[1] =  ymok       ? b2f(hc[p-Wd  ]) : 0.f;
        v[2] = (ymok&&xpok)? b2f(hc[p-Wd+1]) : 0.f;
        v[3] =  xmok       ? b2f(hc[p-1   ]) : 0.f;
        v[4] =               b2f(hc[p     ]);
        v[5] =  xpok       ? b2f(hc[p+1   ]) : 0.f;
        v[6] = (ypok&&xmok)? b2f(hc[p+Wd-1]) : 0.f;
        v[7] =  ypok       ? b2f(hc[p+Wd  ]) : 0.f;
        v[8] = (ypok&&xpok)? b2f(hc[p+Wd+1]) : 0.f;
        #pragma unroll
        for (int g = 0; g < 4; ++g){
            const float* w = uf + (g*Fh+ci)*9;
            acc[g] += v[0]*w[0]+v[1]*w[1]+v[2]*w[2]
                    + v[3]*w[3]+v[4]*w[4]+v[5]*w[5]
                    + v[6]*w[6]+v[7]*w[7]+v[8]*w[8];
        }
    }
    const bf16* z = zx_t + (size_t)b*zx_bstride + p;
    float zi = acc[0] + b2f(z[(size_t)(0*64+fo)*HWp]);
    float zf = acc[1] + b2f(z[(size_t)(1*64+fo)*HWp]);
    float zg = acc[2] + b2f(z[(size_t)(2*64+fo)*HWp]);
    float zo = acc[3] + b2f(z[(size_t)(3*64+fo)*HWp]);
    size_t cidx = ((size_t)b*Fh + fo)*HWp + p;
    float cold = c[cidx];
    float gi = fminf(fmaxf(0.2f*zi+0.5f, 0.f), 1.f);
    float gf = fminf(fmaxf(0.2f*zf+0.5f, 0.f), 1.f);
    float go = fminf(fmaxf(0.2f*zo+0.5f, 0.f), 1.f);
    float sg = 1.f/(1.f+__expf(-zg));
    float cn = gf*cold + gi*sg;
    float hn = go * (1.f/(1.f+__expf(-cn)));
    c[cidx] = cn;
    hout[(size_t)b*ho_bstride + (size_t)fo*HWp + p] = f2b(hn);
    if (WRITE_F32)
        fout[(size_t)b*f_bstride + (size_t)fo*HWp + p] = hn;
}

// BatchNorm over axes (B,T,F,H): per-w sums
__global__ void bn_sum_kernel(const bf16* __restrict__ x, float* __restrict__ sums){
    __shared__ float ls[Wd], lq[Wd];
    for (int i = threadIdx.x; i < Wd; i += blockDim.x){ ls[i]=0.f; lq[i]=0.f; }
    __syncthreads();
    int n = Bn*Tn*Fh*HWp;
    for (int idx = blockIdx.x*blockDim.x + threadIdx.x; idx < n; idx += gridDim.x*blockDim.x){
        float v = b2f(x[idx]);
        int w = idx % Wd;
        atomicAdd(&ls[w], v);
        atomicAdd(&lq[w], v*v);
    }
    __syncthreads();
    for (int i = threadIdx.x; i < Wd; i += blockDim.x){
        atomicAdd(&sums[i], ls[i]);
        atomicAdd(&sums[Wd+i], lq[i]);
    }
}

__global__ void bn_apply_kernel(bf16* __restrict__ x, const float* __restrict__ sums,
                                const float* __restrict__ gamma, const float* __restrict__ beta){
    int idx = blockIdx.x*blockDim.x + threadIdx.x;
    int n = Bn*Tn*Fh*HWp;
    if (idx >= n) return;
    int w = idx % Wd;
    const float N = (float)(Bn*Tn*Fh*Hd);
    float mean = sums[w]/N;
    float var  = sums[Wd+w]/N - mean*mean;
    float sc = rsqrtf(var + 1e-3f) * gamma[w];
    float sh = beta[w] - mean*sc;
    x[idx] = f2b(b2f(x[idx])*sc + sh);
}

extern "C" void kernel_launch(void* const* d_in, const int* in_sizes, int n_in,
                              void* d_out, int out_size, void* d_ws, size_t ws_size,
                              hipStream_t stream){
    const float* xin  = (const float*)d_in[0];
    const float* h1_0 = (const float*)d_in[1];
    const float* c1_0 = (const float*)d_in[2];
    const float* h2_0 = (const float*)d_in[3];
    const float* c2_0 = (const float*)d_in[4];
    const float* W1   = (const float*)d_in[5];
    const float* U1   = (const float*)d_in[6];
    const float* b1   = (const float*)d_in[7];
    const float* W2   = (const float*)d_in[8];
    const float* U2   = (const float*)d_in[9];
    const float* b2   = (const float*)d_in[10];
    const float* gamma= (const float*)d_in[11];
    const float* beta = (const float*)d_in[12];
    float* out = (float*)d_out;   // f32 outputs: x, h1, c1, h2, c2 (flat concat)

    // workspace layout
    char* ws = (char*)d_ws;
    float* W1f = (float*)ws; ws += (size_t)256*4*9*4;
    float* U1f = (float*)ws; ws += (size_t)256*64*9*4;
    float* b1f = (float*)ws; ws += 256*4;
    float* W2f = (float*)ws; ws += (size_t)256*64*9*4;
    float* U2f = (float*)ws; ws += (size_t)256*64*9*4;
    float* b2f = (float*)ws; ws += 256*4;
    float* sums= (float*)ws; ws += 160*4;
    float* cbuf= (float*)ws; ws += (size_t)Bn*Fh*HWp*4;        // 4.9 MB
    float* fscr= (float*)ws; ws += (size_t)Bn*Fh*HWp*4;        // 4.9 MB dummy f32 h dst
    bf16*  h0b = (bf16*)ws;  ws += (size_t)Bn*Fh*HWp*2;        // 2.5 MB
    bf16*  hdb = (bf16*)ws;  ws += (size_t)2*Bn*Fh*HWp*2;      // 4.9 MB double buffer (layer 2)
    bf16*  x1  = (bf16*)ws;  ws += (size_t)Bn*Tn*Fh*HWp*2;     // 29.5 MB
    bf16*  zx  = (bf16*)ws;  ws += (size_t)Bn*Tn*256*HWp*2;    // 118 MB

    const size_t nImg = (size_t)Bn*Fh*HWp;      // 1,228,800
    const size_t xOff = (size_t)Bn*Tn*Fh*HWp;   // 14,745,600
    const int    nAll = Bn*Tn*Fh*HWp;

    // weight/bias permutation (f32 in, f32 out)
    perm_w_kernel<<<(256*4*9+255)/256, 256, 0, stream>>>(W1, W1f, 4);
    perm_w_kernel<<<(256*64*9+255)/256,256, 0, stream>>>(U1, U1f, 64);
    perm_bias_kernel<<<1,256,0,stream>>>(b1, b1f);
    perm_w_kernel<<<(256*64*9+255)/256,256, 0, stream>>>(W2, W2f, 64);
    perm_w_kernel<<<(256*64*9+255)/256,256, 0, stream>>>(U2, U2f, 64);
    perm_bias_kernel<<<1,256,0,stream>>>(b2, b2f);

    dim3 zgrid((HWp+255)/256, 64, Bn*Tn);
    dim3 rgrid((HWp+255)/256, 64, Bn);
    int nImgB = (int)((nImg+255)/256);

    // ---- layer 1 ----
    zx_kernel<4,false><<<zgrid,256,0,stream>>>(xin, W1f, b1f, zx);
    copy_f32_kernel<<<nImgB,256,0,stream>>>(c1_0, cbuf, (int)nImg);
    f32_to_b16_kernel<<<nImgB,256,0,stream>>>(h1_0, h0b, (int)nImg);
    for (int t = 0; t < Tn; ++t){
        const bf16* hp = (t==0) ? h0b : x1 + (size_t)(t-1)*Fh*HWp;
        size_t hb = (t==0) ? (size_t)Fh*HWp : (size_t)Tn*Fh*HWp;
        bf16* ho = x1 + (size_t)t*Fh*HWp;
        if (t == Tn-1)   // last step: also emit f32 h1 (pre-BN) into out
            rec_kernel<true><<<rgrid,256,0,stream>>>(hp, hb, U1f,
                zx + (size_t)t*256*HWp, (size_t)Tn*256*HWp,
                cbuf, ho, (size_t)Tn*Fh*HWp, out + xOff, (size_t)Fh*HWp);
        else
            rec_kernel<false><<<rgrid,256,0,stream>>>(hp, hb, U1f,
                zx + (size_t)t*256*HWp, (size_t)Tn*256*HWp,
                cbuf, ho, (size_t)Tn*Fh*HWp, fscr, (size_t)Fh*HWp);
    }
    // c1 (f32)
    copy_f32_kernel<<<nImgB,256,0,stream>>>(cbuf, out + xOff + nImg, (int)nImg);

    // ---- BatchNorm (in-place on x1) ----
    hipMemsetAsync(sums, 0, 160*4, stream);
    bn_sum_kernel<<<512,256,0,stream>>>(x1, sums);
    bn_apply_kernel<<<(nAll+255)/256,256,0,stream>>>(x1, sums, gamma, beta);

    // ---- layer 2 ----
    zx_kernel<64,true><<<zgrid,256,0,stream>>>(x1, W2f, b2f, zx);
    copy_f32_kernel<<<nImgB,256,0,stream>>>(c2_0, cbuf, (int)nImg);
    f32_to_b16_kernel<<<nImgB,256,0,stream>>>(h2_0, h0b, (int)nImg);
    for (int t = 0; t < Tn; ++t){
        const bf16* hp = (t==0) ? h0b : hdb + (size_t)((t-1)&1)*nImg;
        size_t hb = (size_t)Fh*HWp;
        rec_kernel<true><<<rgrid,256,0,stream>>>(hp, hb, U2f,
            zx + (size_t)t*256*HWp, (size_t)Tn*256*HWp,
            cbuf, hdb + (size_t)(t&1)*nImg, (size_t)Fh*HWp,
            out + (size_t)t*Fh*HWp, (size_t)Tn*Fh*HWp);
    }
    // h2 (contiguous copy of t=11 slice), c2
    copy_h_f32_kernel<<<nImgB,256,0,stream>>>(out + (size_t)(Tn-1)*Fh*HWp, (size_t)Tn*Fh*HWp, out + xOff + 2*nImg);
    copy_f32_kernel<<<nImgB,256,0,stream>>>(cbuf, out + xOff + 3*nImg, (int)nImg);
}

// Round 4
// 1493.504 us; speedup vs baseline: 5.0226x; 5.0226x over previous
//
#include <hip/hip_runtime.h>
#include <hip/hip_bf16.h>

typedef __hip_bfloat16 bf16;
typedef __attribute__((ext_vector_type(8))) short short8;
typedef __attribute__((ext_vector_type(4))) float f32x4;

#define HWp 4800   // H*W
#define Wd 80
#define Hd 60
#define Fh 64
#define Bn 4
#define Tn 12
#define KYS 5992   // LDS shorts per ky plane: 82*72 + 11*8

__device__ __forceinline__ float b2f(bf16 v){ return __bfloat162float(v); }
__device__ __forceinline__ bf16 f2b(float v){ return __float2bfloat16(v); }
__device__ __forceinline__ float bits2f(short s){
    return __uint_as_float(((unsigned)(unsigned short)s) << 16);
}
__device__ __forceinline__ short f2bits(float f){
    bf16 t = f2b(f); short s; __builtin_memcpy(&s, &t, 2); return s;
}

// ---------------- weight prep ----------------
// W1 [256][4][9] f32 -> [fo][g][4][9] f32 (for VALU zx1)
__global__ void perm_w_kernel(const float* __restrict__ src, float* __restrict__ dst, int cin){
    int idx = blockIdx.x*256 + threadIdx.x;
    int n = 256*cin*9;
    if (idx >= n) return;
    int co = idx/(cin*9); int r = idx - co*(cin*9);
    int g = co >> 6, fo = co & 63;
    dst[(fo*4+g)*cin*9 + r] = src[idx];
}
__global__ void perm_bias_kernel(const float* __restrict__ src, float* __restrict__ dst){
    int idx = threadIdx.x; // 256
    int g = idx >> 6, fo = idx & 63;
    dst[fo*4+g] = src[idx];
}
// U/W2 [256co][64ci][3][3] f32 -> bf16 MFMA A-fragments
// Apk[(o*2+c)*16 + ct][lane][8]: co=ct*16+(lane&15), ci=c*32+(lane>>4)*8+j
__global__ void pack_w_kernel(const float* __restrict__ U, short* __restrict__ Apk){
    int d = blockIdx.x*256 + threadIdx.x;
    if (d >= 147456) return;
    int j = d & 7, l = (d>>3) & 63, ct = (d>>9) & 15, oc = d >> 13; // oc 0..17
    int o = oc >> 1, cc = oc & 1;
    int co = ct*16 + (l & 15);
    int ci = cc*32 + (l>>4)*8 + j;
    Apk[d] = f2bits(U[(co*Fh + ci)*9 + o]);
}

// ---------------- small utils ----------------
__global__ void copy_f32_kernel(const float* __restrict__ src, float* __restrict__ dst, int n){
    int idx = blockIdx.x*256+threadIdx.x;
    if (idx < n) dst[idx] = src[idx];
}
__global__ void f32_to_b16_kernel(const float* __restrict__ src, bf16* __restrict__ dst, int n){
    int idx = blockIdx.x*256+threadIdx.x;
    if (idx < n) dst[idx] = f2b(src[idx]);
}
__global__ void copy_h_f32_kernel(const float* __restrict__ src, size_t bstride, float* __restrict__ dst){
    int idx = blockIdx.x*256+threadIdx.x;
    int n = Bn*Fh*HWp;
    if (idx >= n) return;
    int b = idx/(Fh*HWp); int r = idx - b*(Fh*HWp);
    dst[idx] = src[(size_t)b*bstride + r];
}

// ---------------- layer-1 input conv (CIN=4, VALU) ----------------
template<int CIN>
__global__ void zx1_kernel(const float* __restrict__ xin,  // [B*T][CIN][HW]
                           const float* __restrict__ Wf,   // [64][4][CIN][9]
                           const float* __restrict__ bias, // [64][4]
                           bf16* __restrict__ zx)          // [B*T][256][HW]
{
    int p = blockIdx.x*blockDim.x + threadIdx.x;
    if (p >= HWp) return;
    int fo = blockIdx.y, bt = blockIdx.z;
    int y = p / Wd, x = p - y*Wd;
    const float* wf = Wf + fo*4*CIN*9;
    float acc[4] = {bias[fo*4+0], bias[fo*4+1], bias[fo*4+2], bias[fo*4+3]};
    int ym = (y > 0 ? y-1 : 0)*Wd, y0 = y*Wd, yp = (y < Hd-1 ? y+1 : Hd-1)*Wd;
    int xm = (x > 0 ? x-1 : 0),    xp = (x < Wd-1 ? x+1 : Wd-1);
    for (int ci = 0; ci < CIN; ++ci){
        const float* ic = xin + ((size_t)bt*CIN + ci)*HWp;
        float v[9];
        v[0]=ic[ym+xm]; v[1]=ic[ym+x]; v[2]=ic[ym+xp];
        v[3]=ic[y0+xm]; v[4]=ic[y0+x]; v[5]=ic[y0+xp];
        v[6]=ic[yp+xm]; v[7]=ic[yp+x]; v[8]=ic[yp+xp];
        #pragma unroll
        for (int g = 0; g < 4; ++g){
            const float* w = wf + (g*CIN+ci)*9;
            acc[g] += v[0]*w[0]+v[1]*w[1]+v[2]*w[2]
                    + v[3]*w[3]+v[4]*w[4]+v[5]*w[5]
                    + v[6]*w[6]+v[7]*w[7]+v[8]*w[8];
        }
    }
    size_t zbase = (size_t)bt*256*HWp + p;
    #pragma unroll
    for (int g = 0; g < 4; ++g)
        zx[zbase + (size_t)(g*64+fo)*HWp] = f2b(acc[g]);
}

// ---------------- MFMA conv-GEMM core ----------------
// Stage 3 input rows (y-1..y+1) of all 64 ci into LDS, transposed:
// lt[ky][x][ci], x in [0,81] (global x-1..80), addr = ky*KYS + x*72 + (x>>3)*8 + ci
template<bool CLAMP>
__device__ __forceinline__ void stage_tile(const short* __restrict__ src, int y, short* lt){
    const int tid = threadIdx.x;
    for (int ry = 0; ry < 3; ++ry){
        int row = y + ry - 1;
        bool valid = CLAMP ? true : (row >= 0 && row < Hd);
        int rowc = min(max(row, 0), Hd-1);
        short* lp = lt + ry*KYS;
        for (int idx = tid; idx < 640; idx += 256){
            int ci = idx / 10;
            int ch = idx - ci*10;
            int xg = ch*8;                 // global x start
            short8 v = {0,0,0,0,0,0,0,0};
            if (valid) v = *(const short8*)(src + ci*HWp + rowc*Wd + xg);
            #pragma unroll
            for (int j = 0; j < 8; ++j){
                int xl = xg + 1 + j;
                lp[xl*72 + (xl>>3)*8 + ci] = v[j];
            }
        }
        for (int idx = tid; idx < 128; idx += 256){
            int ci = idx & 63; int side = idx >> 6;
            short val = 0;
            if (CLAMP) val = src[ci*HWp + rowc*Wd + (side ? Wd-1 : 0)];
            int xl = side ? 81 : 0;
            lp[xl*72 + (xl>>3)*8 + ci] = val;
        }
    }
}

// acc[g][pt]: wave wv covers co-tiles {g*4+wv} (co = g*64 + wv*16 + rowInTile)
__device__ __forceinline__ void gemm_core(const short* __restrict__ Apk, const short* lt,
                                          int wv, int lane, f32x4 acc[4][5]){
    const int lane15 = lane & 15, grp = lane >> 4;
    for (int o = 0; o < 9; ++o){
        int ky = o/3, kx = o - 3*ky;
        const short* lk = lt + ky*KYS;
        for (int c = 0; c < 2; ++c){
            int ci0 = c*32 + grp*8;
            short8 bf[5];
            #pragma unroll
            for (int pt = 0; pt < 5; ++pt){
                int x = pt*16 + lane15 + kx;
                bf[pt] = *(const short8*)(lk + x*72 + (x>>3)*8 + ci0);
            }
            const short* ab = Apk + ((o*2 + c)*16 + wv)*512 + lane*8;
            #pragma unroll
            for (int g = 0; g < 4; ++g){
                short8 af = *(const short8*)(ab + g*4*512);
                #pragma unroll
                for (int pt = 0; pt < 5; ++pt)
                    acc[g][pt] = __builtin_amdgcn_mfma_f32_16x16x32_bf16(af, bf[pt], acc[g][pt], 0, 0, 0);
            }
        }
    }
}

// one LSTM timestep, fused: z_rec GEMM + gates + c/h update
template<bool WRITE_F32>
__global__ __launch_bounds__(256) void rec_mfma(
    const bf16* __restrict__ hprev, long h_bstride,
    const short* __restrict__ Upk,
    const bf16* __restrict__ zx, int t,          // [b*Tn+t][256][HW]
    float* __restrict__ c,
    bf16* __restrict__ hout, long ho_bstride,
    float* __restrict__ fout, long f_bstride)
{
    __shared__ short lt[3*KYS];
    int y = blockIdx.x, b = blockIdx.y;
    int tid = threadIdx.x, lane = tid & 63, wv = tid >> 6;
    stage_tile<false>((const short*)(hprev + (long)b*h_bstride), y, lt);
    __syncthreads();
    f32x4 acc[4][5];
    #pragma unroll
    for (int g=0;g<4;++g)
        #pragma unroll
        for (int pt=0;pt<5;++pt) acc[g][pt] = (f32x4){0.f,0.f,0.f,0.f};
    gemm_core(Upk, lt, wv, lane, acc);
    int lane15 = lane & 15, grp = lane >> 4;
    const short* zb = (const short*)zx + ((long)(b*Tn + t)*256)*HWp;
    #pragma unroll
    for (int pt = 0; pt < 5; ++pt){
        int p = y*Wd + pt*16 + lane15;
        #pragma unroll
        for (int r = 0; r < 4; ++r){
            int fo = wv*16 + grp*4 + r;
            float zi = acc[0][pt][r] + bits2f(zb[(long)(0*64+fo)*HWp + p]);
            float zf = acc[1][pt][r] + bits2f(zb[(long)(1*64+fo)*HWp + p]);
            float zg = acc[2][pt][r] + bits2f(zb[(long)(2*64+fo)*HWp + p]);
            float zo = acc[3][pt][r] + bits2f(zb[(long)(3*64+fo)*HWp + p]);
            long cidx = ((long)b*Fh + fo)*HWp + p;
            float cold = c[cidx];
            float gi = fminf(fmaxf(0.2f*zi+0.5f, 0.f), 1.f);
            float gf = fminf(fmaxf(0.2f*zf+0.5f, 0.f), 1.f);
            float go = fminf(fmaxf(0.2f*zo+0.5f, 0.f), 1.f);
            float sg = 1.f/(1.f+__expf(-zg));
            float cn = gf*cold + gi*sg;
            float hn = go * (1.f/(1.f+__expf(-cn)));
            c[cidx] = cn;
            hout[(long)b*ho_bstride + (long)fo*HWp + p] = f2b(hn);
            if (WRITE_F32)
                fout[(long)b*f_bstride + (long)fo*HWp + p] = hn;
        }
    }
}

// layer-2 input conv as MFMA GEMM (symmetric clamp), writes zx buffer
__global__ __launch_bounds__(256) void zx_mfma(
    const bf16* __restrict__ xsrc,    // [bt][64][HW] bf16
    const short* __restrict__ Wpk,
    const float* __restrict__ bias,   // [256] f32, co = g*64+fo (original layout)
    bf16* __restrict__ zxb)           // [bt][256][HW]
{
    __shared__ short lt[3*KYS];
    int y = blockIdx.x, img = blockIdx.y;
    int tid = threadIdx.x, lane = tid & 63, wv = tid >> 6;
    stage_tile<true>((const short*)(xsrc + (long)img*Fh*HWp), y, lt);
    __syncthreads();
    f32x4 acc[4][5];
    #pragma unroll
    for (int g=0;g<4;++g)
        #pragma unroll
        for (int pt=0;pt<5;++pt) acc[g][pt] = (f32x4){0.f,0.f,0.f,0.f};
    gemm_core(Wpk, lt, wv, lane, acc);
    int lane15 = lane & 15, grp = lane >> 4;
    #pragma unroll
    for (int pt = 0; pt < 5; ++pt){
        int p = y*Wd + pt*16 + lane15;
        #pragma unroll
        for (int r = 0; r < 4; ++r){
            int fo = wv*16 + grp*4 + r;
            #pragma unroll
            for (int g = 0; g < 4; ++g){
                int co = g*64 + fo;
                zxb[((long)img*256 + co)*HWp + p] = f2b(acc[g][pt][r] + bias[co]);
            }
        }
    }
}

// ---------------- BatchNorm ----------------
#define BN_GRID 480
__global__ void bn_sum_kernel2(const short* __restrict__ x, float* __restrict__ sums){
    __shared__ float ls[160];
    int tid = threadIdx.x;
    if (tid < 160) ls[tid] = 0.f;
    __syncthreads();
    int gid = blockIdx.x*256 + tid;
    const int stride = BN_GRID*256;
    const int nvec = Bn*Tn*Fh*HWp/8;
    float s[8] = {0,0,0,0,0,0,0,0}, q[8] = {0,0,0,0,0,0,0,0};
    for (int v = gid; v < nvec; v += stride){
        short8 hv = *(const short8*)(x + (long)v*8);
        #pragma unroll
        for (int j = 0; j < 8; ++j){
            float f = bits2f(hv[j]);
            s[j] += f; q[j] += f*f;
        }
    }
    int b0 = (gid % 10)*8;
    #pragma unroll
    for (int j = 0; j < 8; ++j){
        atomicAdd(&ls[b0+j], s[j]);
        atomicAdd(&ls[80+b0+j], q[j]);
    }
    __syncthreads();
    if (tid < 160) atomicAdd(&sums[tid], ls[tid]);
}
__global__ void bn_coef_kernel(const float* __restrict__ sums, const float* __restrict__ g,
                               const float* __restrict__ bt, float* __restrict__ coef){
    int w = threadIdx.x; // 80
    const float N = (float)(Bn*Tn*Fh*Hd);
    float mean = sums[w]/N;
    float var  = sums[80+w]/N - mean*mean;
    float sc = rsqrtf(var + 1e-3f)*g[w];
    coef[w] = sc;
    coef[80+w] = bt[w] - mean*sc;
}
__global__ void bn_apply_kernel2(short* __restrict__ x, const float* __restrict__ coef){
    int gid = blockIdx.x*256 + threadIdx.x;
    const int stride = BN_GRID*256;
    const int nvec = Bn*Tn*Fh*HWp/8;
    int b0 = (gid % 10)*8;
    float sc[8], sh[8];
    #pragma unroll
    for (int j = 0; j < 8; ++j){ sc[j] = coef[b0+j]; sh[j] = coef[80+b0+j]; }
    for (int v = gid; v < nvec; v += stride){
        short8 hv = *(short8*)(x + (long)v*8);
        #pragma unroll
        for (int j = 0; j < 8; ++j)
            hv[j] = f2bits(bits2f(hv[j])*sc[j] + sh[j]);
        *(short8*)(x + (long)v*8) = hv;
    }
}

extern "C" void kernel_launch(void* const* d_in, const int* in_sizes, int n_in,
                              void* d_out, int out_size, void* d_ws, size_t ws_size,
                              hipStream_t stream){
    const float* xin  = (const float*)d_in[0];
    const float* h1_0 = (const float*)d_in[1];
    const float* c1_0 = (const float*)d_in[2];
    const float* h2_0 = (const float*)d_in[3];
    const float* c2_0 = (const float*)d_in[4];
    const float* W1   = (const float*)d_in[5];
    const float* U1   = (const float*)d_in[6];
    const float* b1   = (const float*)d_in[7];
    const float* W2   = (const float*)d_in[8];
    const float* U2   = (const float*)d_in[9];
    const float* b2   = (const float*)d_in[10];
    const float* gamma= (const float*)d_in[11];
    const float* beta = (const float*)d_in[12];
    float* out = (float*)d_out;

    char* ws = (char*)d_ws;
    float* W1f = (float*)ws; ws += (size_t)256*4*9*4;       // 36864
    float* b1f = (float*)ws; ws += 1024;
    short* U1p = (short*)ws; ws += (size_t)147456*2;        // 294912
    short* W2p = (short*)ws; ws += (size_t)147456*2;
    short* U2p = (short*)ws; ws += (size_t)147456*2;
    float* sums= (float*)ws; ws += 1024;
    float* coef= (float*)ws; ws += 1024;
    float* cbuf= (float*)ws; ws += (size_t)Bn*Fh*HWp*4;
    bf16*  h0b = (bf16*)ws;  ws += (size_t)Bn*Fh*HWp*2;
    bf16*  hdb = (bf16*)ws;  ws += (size_t)2*Bn*Fh*HWp*2;
    bf16*  x1  = (bf16*)ws;  ws += (size_t)Bn*Tn*Fh*HWp*2;
    bf16*  zx  = (bf16*)ws;  ws += (size_t)Bn*Tn*256*HWp*2;

    const size_t nImg = (size_t)Bn*Fh*HWp;      // 1,228,800
    const size_t xOff = (size_t)Bn*Tn*Fh*HWp;   // 14,745,600
    const long   sHT  = (long)Fh*HWp;           // 307,200 (one [64][HW] image)
    const long   sBT  = (long)Tn*Fh*HWp;        // 3,686,400

    perm_w_kernel<<<(256*4*9+255)/256, 256, 0, stream>>>(W1, W1f, 4);
    perm_bias_kernel<<<1,256,0,stream>>>(b1, b1f);
    pack_w_kernel<<<576,256,0,stream>>>(U1, U1p);
    pack_w_kernel<<<576,256,0,stream>>>(W2, W2p);
    pack_w_kernel<<<576,256,0,stream>>>(U2, U2p);

    int nImgB = (int)((nImg+255)/256);
    dim3 zgrid1((HWp+255)/256, 64, Bn*Tn);
    dim3 ggrid(Hd, Bn);
    dim3 zgrid2(Hd, Bn*Tn);

    // ---- layer 1 ----
    zx1_kernel<4><<<zgrid1,256,0,stream>>>(xin, W1f, b1f, zx);
    copy_f32_kernel<<<nImgB,256,0,stream>>>(c1_0, cbuf, (int)nImg);
    f32_to_b16_kernel<<<nImgB,256,0,stream>>>(h1_0, h0b, (int)nImg);
    for (int t = 0; t < Tn; ++t){
        const bf16* hp = (t==0) ? h0b : x1 + (size_t)(t-1)*sHT;
        long hb = (t==0) ? sHT : sBT;
        bf16* ho = x1 + (size_t)t*sHT;
        if (t == Tn-1)
            rec_mfma<true><<<ggrid,256,0,stream>>>(hp, hb, U1p, zx, t, cbuf,
                ho, sBT, out + xOff, sHT);
        else
            rec_mfma<false><<<ggrid,256,0,stream>>>(hp, hb, U1p, zx, t, cbuf,
                ho, sBT, nullptr, 0);
    }
    copy_f32_kernel<<<nImgB,256,0,stream>>>(cbuf, out + xOff + nImg, (int)nImg);

    // ---- BatchNorm (in-place on x1) ----
    hipMemsetAsync(sums, 0, 640, stream);
    bn_sum_kernel2<<<BN_GRID,256,0,stream>>>((const short*)x1, sums);
    bn_coef_kernel<<<1,80,0,stream>>>(sums, gamma, beta, coef);
    bn_apply_kernel2<<<BN_GRID,256,0,stream>>>((short*)x1, coef);

    // ---- layer 2 ----
    zx_mfma<<<zgrid2,256,0,stream>>>(x1, W2p, b2, zx);
    copy_f32_kernel<<<nImgB,256,0,stream>>>(c2_0, cbuf, (int)nImg);
    f32_to_b16_kernel<<<nImgB,256,0,stream>>>(h2_0, h0b, (int)nImg);
    for (int t = 0; t < Tn; ++t){
        const bf16* hp = (t==0) ? h0b : hdb + (size_t)((t-1)&1)*nImg;
        long hb = sHT;
        rec_mfma<true><<<ggrid,256,0,stream>>>(hp, hb, U2p, zx, t, cbuf,
            hdb + (size_t)(t&1)*nImg, sHT, out + (size_t)t*sHT, sBT);
    }
    copy_h_f32_kernel<<<nImgB,256,0,stream>>>(out + (size_t)(Tn-1)*sHT, sBT, out + xOff + 2*nImg);
    copy_f32_kernel<<<nImgB,256,0,stream>>>(cbuf, out + xOff + 3*nImg, (int)nImg);
}

// Round 6
// 998.448 us; speedup vs baseline: 7.5129x; 1.4958x over previous
//
#include <hip/hip_runtime.h>
#include <hip/hip_bf16.h>

typedef __hip_bfloat16 bf16;
typedef __attribute__((ext_vector_type(8))) short sh8;
typedef __attribute__((ext_vector_type(4))) short sh4;
typedef __attribute__((ext_vector_type(4))) float f32x4;

#define HWp 4800
#define Wd 80
#define Hd 60
#define Fh 64
#define Bn 4
#define Tn 12
#define KYS 5248         // 82*64 shorts per ky plane
#define sHT ((long)Fh*HWp)

__device__ __forceinline__ float b2f(bf16 v){ return __bfloat162float(v); }
__device__ __forceinline__ bf16 f2b(float v){ return __float2bfloat16(v); }
__device__ __forceinline__ float bits2f(short s){
    return __uint_as_float(((unsigned)(unsigned short)s) << 16);
}
__device__ __forceinline__ short f2bits(float f){
    bf16 t = f2b(f); short s; __builtin_memcpy(&s, &t, 2); return s;
}

// ---------------- weight prep ----------------
__global__ void perm_w_kernel(const float* __restrict__ src, float* __restrict__ dst, int cin){
    int idx = blockIdx.x*256 + threadIdx.x;
    int n = 256*cin*9;
    if (idx >= n) return;
    int co = idx/(cin*9); int r = idx - co*(cin*9);
    int g = co >> 6, fo = co & 63;
    dst[(fo*4+g)*cin*9 + r] = src[idx];
}
__global__ void perm_bias_kernel(const float* __restrict__ src, float* __restrict__ dst){
    int idx = threadIdx.x; // 256
    int g = idx >> 6, fo = idx & 63;
    dst[fo*4+g] = src[idx];
}
// U/W2 [256co][64ci][3][3] f32 -> bf16 MFMA A-fragments
__global__ void pack_w_kernel(const float* __restrict__ U, short* __restrict__ Apk){
    int d = blockIdx.x*256 + threadIdx.x;
    if (d >= 147456) return;
    int j = d & 7, l = (d>>3) & 63, ct = (d>>9) & 15, oc = d >> 13;
    int o = oc >> 1, cc = oc & 1;
    int co = ct*16 + (l & 15);
    int ci = cc*32 + (l>>4)*8 + j;
    Apk[d] = f2bits(U[(co*Fh + ci)*9 + o]);
}

// ---------------- small utils ----------------
__global__ void copy_f32_kernel(const float* __restrict__ src, float* __restrict__ dst, int n){
    int idx = blockIdx.x*256+threadIdx.x;
    if (idx < n) dst[idx] = src[idx];
}
__global__ void copy_h_f32_kernel(const float* __restrict__ src, long bstride, float* __restrict__ dst){
    long idx = (long)blockIdx.x*256+threadIdx.x;
    long n = (long)Bn*Fh*HWp;
    if (idx >= n) return;
    long b = idx/(Fh*HWp); long r = idx - b*(Fh*HWp);
    dst[idx] = src[b*bstride + r];
}
// f32 std [b][fo][p] -> bf16 channel-last [b][p][fo]
__global__ void h0cl_kernel(const float* __restrict__ src, bf16* __restrict__ dst){
    long idx = (long)blockIdx.x*256 + threadIdx.x;
    if (idx >= (long)Bn*Fh*HWp) return;
    int fo = (int)(idx & 63);
    long rest = idx >> 6;
    int p = (int)(rest % HWp);
    int b = (int)(rest / HWp);
    dst[idx] = f2b(src[((long)b*Fh + fo)*HWp + p]);
}

// ---------------- layer-1 input conv (CIN=4, VALU), gate-packed z out ----------------
__global__ void zx1_kernel(const float* __restrict__ xin,  // [B*T][4][HW]
                           const float* __restrict__ Wf,   // [64fo][4g][4ci][9]
                           const float* __restrict__ bias, // [64fo][4g]
                           short* __restrict__ zx)         // [b][t][p][fo][g]
{
    int p = blockIdx.x*blockDim.x + threadIdx.x;
    if (p >= HWp) return;
    int fo = blockIdx.y, bt = blockIdx.z;
    int y = p / Wd, x = p - y*Wd;
    const float* wf = Wf + fo*4*4*9;
    float acc[4] = {bias[fo*4+0], bias[fo*4+1], bias[fo*4+2], bias[fo*4+3]};
    int ym = (y > 0 ? y-1 : 0)*Wd, y0 = y*Wd, yp = (y < Hd-1 ? y+1 : Hd-1)*Wd;
    int xm = (x > 0 ? x-1 : 0),    xp = (x < Wd-1 ? x+1 : Wd-1);
    for (int ci = 0; ci < 4; ++ci){
        const float* ic = xin + ((long)bt*4 + ci)*HWp;
        float v[9];
        v[0]=ic[ym+xm]; v[1]=ic[ym+x]; v[2]=ic[ym+xp];
        v[3]=ic[y0+xm]; v[4]=ic[y0+x]; v[5]=ic[y0+xp];
        v[6]=ic[yp+xm]; v[7]=ic[yp+x]; v[8]=ic[yp+xp];
        #pragma unroll
        for (int g = 0; g < 4; ++g){
            const float* w = wf + (g*4+ci)*9;
            acc[g] += v[0]*w[0]+v[1]*w[1]+v[2]*w[2]
                    + v[3]*w[3]+v[4]*w[4]+v[5]*w[5]
                    + v[6]*w[6]+v[7]*w[7]+v[8]*w[8];
        }
    }
    sh4 o4 = { f2bits(acc[0]), f2bits(acc[1]), f2bits(acc[2]), f2bits(acc[3]) };
    *(sh4*)(zx + ((long)bt*HWp + p)*256 + fo*4) = o4;
}

// ---------------- channel-last LDS stage + MFMA core ----------------
// LDS lt[3][82][64] shorts; chunk (x_l, cc) stored at x_l*64 + ((cc^(x_l&7))*8)
template<bool CLAMP>
__device__ __forceinline__ void stage_cl(const short* __restrict__ src, int y, short* lt){
    const int tid = threadIdx.x;
    #pragma unroll
    for (int it = 0; it < 8; ++it){
        int n = it*256 + tid;
        if (n < 1968){
            int row = n/656, rem = n - row*656;
            int rg = y + row - 1;
            bool rvalid = CLAMP ? true : (rg >= 0 && rg < Hd);
            rg = min(max(rg,0), Hd-1);
            int xg, cc, xl; bool cvalid = true;
            if (rem < 640){ xg = rem>>3; cc = rem&7; xl = xg+1; }
            else if (rem < 648){ xg = 0; cc = rem-640; xl = 0; cvalid = CLAMP; }
            else { xg = Wd-1; cc = rem-648; xl = 81; cvalid = CLAMP; }
            sh8 v = {0,0,0,0,0,0,0,0};
            if (rvalid && cvalid) v = *(const sh8*)(src + ((long)(rg*Wd + xg)*64 + cc*8));
            *(sh8*)(lt + row*KYS + xl*64 + ((cc ^ (xl&7))<<3)) = v;
        }
    }
}

__device__ __forceinline__ void gemm_core(const short* __restrict__ Apk, const short* lt,
                                          int wv, int lane, f32x4 acc[4][5]){
    const int lane15 = lane & 15, grp = lane >> 4;
    #pragma unroll
    for (int o = 0; o < 9; ++o){
        int ky = o/3, kx = o - 3*(o/3);
        const short* lk = lt + ky*KYS;
        #pragma unroll
        for (int c = 0; c < 2; ++c){
            sh8 bfr[5];
            #pragma unroll
            for (int pt = 0; pt < 5; ++pt){
                int xl = pt*16 + lane15 + kx;
                int cc = (c*4 + grp) ^ (xl & 7);
                bfr[pt] = *(const sh8*)(lk + xl*64 + cc*8);
            }
            const short* ab = Apk + ((long)((o*2 + c)*16 + wv))*512 + lane*8;
            #pragma unroll
            for (int g = 0; g < 4; ++g){
                sh8 af = *(const sh8*)(ab + (long)g*4*512);
                #pragma unroll
                for (int pt = 0; pt < 5; ++pt)
                    acc[g][pt] = __builtin_amdgcn_mfma_f32_16x16x32_bf16(af, bfr[pt], acc[g][pt], 0, 0, 0);
            }
        }
    }
}

// ---------------- one LSTM timestep (per-step launch) ----------------
// hprev: + b*h_bstride, layout [p][fo] bf16. hout: + b*sHT, layout [p][fo].
// zx_t: + b*z_bstride, gate-packed [p][fo][g]. fx: fx[b*f_bstride + fo*HWp + p] (f32, std).
template<bool WRITE_FX>
__global__ __launch_bounds__(256) void rec_step(
    const bf16* __restrict__ hprev, long h_bstride,
    const short* __restrict__ Upk,
    const short* __restrict__ zx_t, long z_bstride,
    float* __restrict__ c,
    bf16* __restrict__ hout,
    float* __restrict__ fx, long f_bstride)
{
    __shared__ short lt[3*KYS];
    int y = blockIdx.x, b = blockIdx.y;
    int tid = threadIdx.x, lane = tid & 63, wv = tid >> 6;
    int lane15 = lane & 15, grp = lane >> 4;

    stage_cl<false>((const short*)hprev + (long)b*h_bstride, y, lt);

    // prefetch z (gate-packed) and c while the stage's LDS writes drain
    sh4 zq[5][4]; float cold[5][4];
    const short* zb = zx_t + (long)b*z_bstride;
    #pragma unroll
    for (int pt = 0; pt < 5; ++pt){
        int p = y*Wd + pt*16 + lane15;
        #pragma unroll
        for (int r = 0; r < 4; ++r){
            int fo = wv*16 + grp*4 + r;
            zq[pt][r] = *(const sh4*)(zb + (long)p*256 + fo*4);
            cold[pt][r] = c[((long)b*Fh + fo)*HWp + p];
        }
    }
    __syncthreads();

    f32x4 acc[4][5];
    #pragma unroll
    for (int g = 0; g < 4; ++g)
        #pragma unroll
        for (int pt = 0; pt < 5; ++pt) acc[g][pt] = (f32x4){0.f,0.f,0.f,0.f};
    gemm_core(Upk, lt, wv, lane, acc);

    #pragma unroll
    for (int pt = 0; pt < 5; ++pt){
        int p = y*Wd + pt*16 + lane15;
        #pragma unroll
        for (int r = 0; r < 4; ++r){
            int fo = wv*16 + grp*4 + r;
            float zi = acc[0][pt][r] + bits2f(zq[pt][r][0]);
            float zf = acc[1][pt][r] + bits2f(zq[pt][r][1]);
            float zg = acc[2][pt][r] + bits2f(zq[pt][r][2]);
            float zo = acc[3][pt][r] + bits2f(zq[pt][r][3]);
            float gi = fminf(fmaxf(0.2f*zi+0.5f, 0.f), 1.f);
            float gf = fminf(fmaxf(0.2f*zf+0.5f, 0.f), 1.f);
            float go = fminf(fmaxf(0.2f*zo+0.5f, 0.f), 1.f);
            float sg = 1.f/(1.f+__expf(-zg));
            float cn = gf*cold[pt][r] + gi*sg;
            float hn = go * (1.f/(1.f+__expf(-cn)));
            c[((long)b*Fh + fo)*HWp + p] = cn;
            hout[((long)b*sHT) + (long)p*64 + fo] = f2b(hn);
            if (WRITE_FX)
                fx[(long)b*f_bstride + (long)fo*HWp + p] = hn;
        }
    }
}

// ---------------- layer-2 input conv, MFMA, channel-last in, gate-packed out ----------------
__global__ __launch_bounds__(256,2) void zx_mfma(
    const bf16* __restrict__ x1,     // [t][b][p][fo] cl bf16
    const short* __restrict__ Wpk,
    const float* __restrict__ bias,  // [256] co = g*64+fo
    short* __restrict__ zxb)         // [b][t][p][fo][g]
{
    __shared__ short lt[3*KYS];
    int y = blockIdx.x, img = blockIdx.y;   // img = t*Bn + b
    int t = img / Bn, b = img - t*Bn;
    int tid = threadIdx.x, lane = tid & 63, wv = tid >> 6;
    int lane15 = lane & 15, grp = lane >> 4;
    stage_cl<true>((const short*)x1 + (long)img*sHT, y, lt);
    __syncthreads();
    f32x4 acc[4][5];
    #pragma unroll
    for (int g = 0; g < 4; ++g)
        #pragma unroll
        for (int pt = 0; pt < 5; ++pt) acc[g][pt] = (f32x4){0.f,0.f,0.f,0.f};
    gemm_core(Wpk, lt, wv, lane, acc);
    short* zb = zxb + ((long)(b*Tn + t))*HWp*256;
    #pragma unroll
    for (int pt = 0; pt < 5; ++pt){
        int p = y*Wd + pt*16 + lane15;
        #pragma unroll
        for (int r = 0; r < 4; ++r){
            int fo = wv*16 + grp*4 + r;
            sh4 o4 = { f2bits(acc[0][pt][r] + bias[fo]),
                       f2bits(acc[1][pt][r] + bias[64+fo]),
                       f2bits(acc[2][pt][r] + bias[128+fo]),
                       f2bits(acc[3][pt][r] + bias[192+fo]) };
            *(sh4*)(zb + (long)p*256 + fo*4) = o4;
        }
    }
}

// ---------------- BatchNorm (channel-last x1) ----------------
#define BN_GRID 480
__global__ void bn_sum_cl(const short* __restrict__ x, float* __restrict__ sums){
    __shared__ float ls[160];
    int tid = threadIdx.x;
    if (tid < 160) ls[tid] = 0.f;
    __syncthreads();
    long gid = (long)blockIdx.x*256 + tid;
    const long nchunk = (long)Bn*Tn*HWp*8;   // sh8 chunks
    float s = 0.f, q = 0.f;
    for (long ch = gid; ch < nchunk; ch += (long)BN_GRID*256){
        sh8 v = *(const sh8*)(x + ch*8);
        #pragma unroll
        for (int j = 0; j < 8; ++j){ float f = bits2f(v[j]); s += f; q += f*f; }
    }
    int w = (int)((gid>>3) % Wd);   // constant along stride (stride/8 % 80 == 0)
    atomicAdd(&ls[w], s); atomicAdd(&ls[80+w], q);
    __syncthreads();
    if (tid < 160) atomicAdd(&sums[tid], ls[tid]);
}
__global__ void bn_coef_kernel(const float* __restrict__ sums, const float* __restrict__ g,
                               const float* __restrict__ bt, float* __restrict__ coef){
    int w = threadIdx.x; // 80
    const float N = (float)(Bn*Tn*Fh*Hd);
    float mean = sums[w]/N;
    float var  = sums[80+w]/N - mean*mean;
    float sc = rsqrtf(var + 1e-3f)*g[w];
    coef[w] = sc;
    coef[80+w] = bt[w] - mean*sc;
}
__global__ void bn_apply_cl(short* __restrict__ x, const float* __restrict__ coef){
    long gid = (long)blockIdx.x*256 + threadIdx.x;
    const long nchunk = (long)Bn*Tn*HWp*8;
    int w = (int)((gid>>3) % Wd);
    float sc = coef[w], sh = coef[80+w];
    for (long ch = gid; ch < nchunk; ch += (long)BN_GRID*256){
        sh8 v = *(sh8*)(x + ch*8);
        #pragma unroll
        for (int j = 0; j < 8; ++j) v[j] = f2bits(bits2f(v[j])*sc + sh);
        *(sh8*)(x + ch*8) = v;
    }
}

extern "C" void kernel_launch(void* const* d_in, const int* in_sizes, int n_in,
                              void* d_out, int out_size, void* d_ws, size_t ws_size,
                              hipStream_t stream){
    const float* xin  = (const float*)d_in[0];
    const float* h1_0 = (const float*)d_in[1];
    const float* c1_0 = (const float*)d_in[2];
    const float* h2_0 = (const float*)d_in[3];
    const float* c2_0 = (const float*)d_in[4];
    const float* W1   = (const float*)d_in[5];
    const float* U1   = (const float*)d_in[6];
    const float* b1   = (const float*)d_in[7];
    const float* W2   = (const float*)d_in[8];
    const float* U2   = (const float*)d_in[9];
    const float* b2   = (const float*)d_in[10];
    const float* gamma= (const float*)d_in[11];
    const float* beta = (const float*)d_in[12];
    float* out = (float*)d_out;

    char* ws = (char*)d_ws;
    float* W1f = (float*)ws; ws += (size_t)256*4*9*4;
    float* b1f = (float*)ws; ws += 1024;
    short* U1p = (short*)ws; ws += (size_t)147456*2;
    short* W2p = (short*)ws; ws += (size_t)147456*2;
    short* U2p = (short*)ws; ws += (size_t)147456*2;
    float* sums= (float*)ws; ws += 1024;
    float* coef= (float*)ws; ws += 1024;
    float* cbuf= (float*)ws; ws += (size_t)Bn*Fh*HWp*4;
    bf16*  h0b = (bf16*)ws; ws += (size_t)Bn*Fh*HWp*2;
    bf16*  hdb = (bf16*)ws; ws += (size_t)2*Bn*Fh*HWp*2;
    bf16*  x1  = (bf16*)ws; ws += (size_t)Bn*Tn*Fh*HWp*2;     // [t][b][p][fo]
    short* zx  = (short*)ws; ws += (size_t)Bn*Tn*256*HWp*2;   // [b][t][p][fo][g]

    const long nImg = (long)Bn*Fh*HWp;
    const long xOff = (long)Bn*Tn*Fh*HWp;
    int nImgB = (int)((nImg+255)/256);

    perm_w_kernel<<<(256*4*9+255)/256, 256, 0, stream>>>(W1, W1f, 4);
    perm_bias_kernel<<<1,256,0,stream>>>(b1, b1f);
    pack_w_kernel<<<576,256,0,stream>>>(U1, U1p);
    pack_w_kernel<<<576,256,0,stream>>>(W2, W2p);
    pack_w_kernel<<<576,256,0,stream>>>(U2, U2p);

    dim3 rgrid(Hd, Bn);
    const long zstep = (long)HWp*256;     // per-t z stride (elements)
    const long zbstr = (long)Tn*HWp*256;  // per-b z stride

    // ---- layer 1 ----
    dim3 zgrid1((HWp+255)/256, 64, Bn*Tn);
    zx1_kernel<<<zgrid1,256,0,stream>>>(xin, W1f, b1f, zx);
    copy_f32_kernel<<<nImgB,256,0,stream>>>(c1_0, cbuf, (int)nImg);
    h0cl_kernel<<<nImgB,256,0,stream>>>(h1_0, h0b);
    for (int t = 0; t < Tn; ++t){
        const bf16* hp = (t==0) ? h0b : x1 + (long)(t-1)*Bn*sHT;
        bf16* ho = x1 + (long)t*Bn*sHT;
        if (t == Tn-1)
            rec_step<true><<<rgrid,256,0,stream>>>(hp, sHT, U1p,
                zx + (long)t*zstep, zbstr, cbuf, ho, out + xOff, sHT);
        else
            rec_step<false><<<rgrid,256,0,stream>>>(hp, sHT, U1p,
                zx + (long)t*zstep, zbstr, cbuf, ho, nullptr, 0);
    }
    copy_f32_kernel<<<nImgB,256,0,stream>>>(cbuf, out + xOff + nImg, (int)nImg);

    // ---- BatchNorm (in-place on x1, channel-last) ----
    hipMemsetAsync(sums, 0, 640, stream);
    bn_sum_cl<<<BN_GRID,256,0,stream>>>((const short*)x1, sums);
    bn_coef_kernel<<<1,80,0,stream>>>(sums, gamma, beta, coef);
    bn_apply_cl<<<BN_GRID,256,0,stream>>>((short*)x1, coef);

    // ---- layer 2 ----
    dim3 zgrid2(Hd, Bn*Tn);
    zx_mfma<<<zgrid2,256,0,stream>>>(x1, W2p, b2, zx);
    copy_f32_kernel<<<nImgB,256,0,stream>>>(c2_0, cbuf, (int)nImg);
    h0cl_kernel<<<nImgB,256,0,stream>>>(h2_0, h0b);
    for (int t = 0; t < Tn; ++t){
        const bf16* hp = (t==0) ? h0b : hdb + (long)((t-1)&1)*Bn*sHT;
        bf16* ho = hdb + (long)(t&1)*Bn*sHT;
        rec_step<true><<<rgrid,256,0,stream>>>(hp, sHT, U2p,
            zx + (long)t*zstep, zbstr, cbuf, ho, out + (long)t*sHT, (long)Tn*sHT);
    }
    copy_h_f32_kernel<<<nImgB,256,0,stream>>>(out + (long)(Tn-1)*sHT, (long)Tn*sHT, out + xOff + 2*nImg);
    copy_f32_kernel<<<nImgB,256,0,stream>>>(cbuf, out + xOff + 3*nImg, (int)nImg);
}